// Round 1
// baseline (1223.161 us; speedup 1.0000x reference)
//
#include <hip/hip_runtime.h>
#include <stdint.h>
#include <stddef.h>

#define B_  16
#define U_  512
#define LX_ 1024
#define LY_ 1024
#define H_  8
#define D_  64

// ---------------------------------------------------------------------------
// Detect whether the mask buffer is uint8 (1B/elem) or int32 (4B/elem).
// If int32 with 0/1 values, every 32-bit word of the first 1024 is <= 1.
// If uint8-packed random 0/1 bytes, only ~1/8 of words are <= 1.
// ---------------------------------------------------------------------------
__global__ void detect_kernel(const unsigned* __restrict__ mask, int* __restrict__ flag) {
    __shared__ int s;
    if (threadIdx.x == 0) s = 0;
    __syncthreads();
    int c = 0;
    for (int i = threadIdx.x; i < 1024; i += 256) c += (mask[i] <= 1u) ? 1 : 0;
    atomicAdd(&s, c);
    __syncthreads();
    if (threadIdx.x == 0) *flag = (s >= 1000) ? 1 : 0;
}

// ---------------------------------------------------------------------------
// n_el[b,x] = max(sum_y mask[b,x,y], 1)  as float. One wave per row.
// ---------------------------------------------------------------------------
__global__ __launch_bounds__(256) void nel_kernel(const void* __restrict__ mask,
                                                  const int* __restrict__ flag,
                                                  float* __restrict__ nel) {
    int row  = blockIdx.x * 4 + (threadIdx.x >> 6);   // 0 .. B*LX-1
    int lane = threadIdx.x & 63;
    int cnt = 0;
    if (*flag) {
        const int* m = (const int*)mask + (size_t)row * LY_;
        for (int i = lane; i < LY_; i += 64) cnt += (m[i] != 0) ? 1 : 0;
    } else {
        const uint8_t* m = (const uint8_t*)mask + (size_t)row * LY_;
        uint4 v = ((const uint4*)m)[lane];            // 16 bytes, bytes are 0/1
        unsigned a = (v.x & 0x01010101u) + (v.y & 0x01010101u)
                   + (v.z & 0x01010101u) + (v.w & 0x01010101u);
        // byte sums <= 4, no carry: horizontal add
        cnt = (int)((a * 0x01010101u) >> 24);
    }
    for (int off = 32; off > 0; off >>= 1) cnt += __shfl_down(cnt, off, 64);
    if (lane == 0) nel[row] = (float)(cnt > 0 ? cnt : 1);
}

// ---------------------------------------------------------------------------
// Out[b] = W(512x512) @ X[b](512xL).  64x64 tile, bk=16, 4x4 microtile.
// grid = (L/64, 8, B), block = 256
// ---------------------------------------------------------------------------
__global__ __launch_bounds__(256) void gemm512(const float* __restrict__ W,
                                               const float* __restrict__ X,
                                               float* __restrict__ Out, int L) {
    const int l0 = blockIdx.x * 64;
    const int o0 = blockIdx.y * 64;
    const int b  = blockIdx.z;
    const float* Xb = X + (size_t)b * U_ * L;
    float*       Ob = Out + (size_t)b * U_ * L;

    __shared__ float Ws[16][68];   // [u][o]
    __shared__ float Xs[16][68];   // [u][l]

    const int tid = threadIdx.x;
    const int tx = tid & 15;       // l group
    const int ty = tid >> 4;       // o group

    float acc[4][4];
    #pragma unroll
    for (int i = 0; i < 4; ++i)
        #pragma unroll
        for (int j = 0; j < 4; ++j) acc[i][j] = 0.f;

    for (int u0 = 0; u0 < U_; u0 += 16) {
        // load W tile (64 o x 16 u), transposed into Ws[u][o]
        {
            int o  = tid >> 2;
            int j4 = (tid & 3) * 4;
            float4 wv = *(const float4*)&W[(size_t)(o0 + o) * U_ + u0 + j4];
            Ws[j4 + 0][o] = wv.x; Ws[j4 + 1][o] = wv.y;
            Ws[j4 + 2][o] = wv.z; Ws[j4 + 3][o] = wv.w;
        }
        // load X tile (16 u x 64 l)
        {
            int j  = tid >> 4;
            int i4 = (tid & 15) * 4;
            *(float4*)&Xs[j][i4] = *(const float4*)&Xb[(size_t)(u0 + j) * L + l0 + i4];
        }
        __syncthreads();
        #pragma unroll
        for (int u = 0; u < 16; ++u) {
            float4 wv = *(const float4*)&Ws[u][ty * 4];
            float4 xv = *(const float4*)&Xs[u][tx * 4];
            acc[0][0] += wv.x * xv.x; acc[0][1] += wv.x * xv.y; acc[0][2] += wv.x * xv.z; acc[0][3] += wv.x * xv.w;
            acc[1][0] += wv.y * xv.x; acc[1][1] += wv.y * xv.y; acc[1][2] += wv.y * xv.z; acc[1][3] += wv.y * xv.w;
            acc[2][0] += wv.z * xv.x; acc[2][1] += wv.z * xv.y; acc[2][2] += wv.z * xv.z; acc[2][3] += wv.z * xv.w;
            acc[3][0] += wv.w * xv.x; acc[3][1] += wv.w * xv.y; acc[3][2] += wv.w * xv.z; acc[3][3] += wv.w * xv.w;
        }
        __syncthreads();
    }
    #pragma unroll
    for (int i = 0; i < 4; ++i) {
        float4 v = make_float4(acc[i][0], acc[i][1], acc[i][2], acc[i][3]);
        *(float4*)&Ob[(size_t)(o0 + ty * 4 + i) * L + l0 + tx * 4] = v;
    }
}

// ---------------------------------------------------------------------------
// Fused ReLU-attention. Block = (xt, h, b), 256 threads, 32 x-positions.
//   S[x,y] = mask ? relu(Q[:,x].K[:,y]) * 0.125 : 0   (y-tiles of 64)
//   C[d,x] = sum_y S[x,y] K[d,y]
//   E[d,x] = 0.5 * (Q[d,x] + C[d,x]/n_el[x])   written in place over Q
// ---------------------------------------------------------------------------
__global__ __launch_bounds__(256) void attn_kernel(float* __restrict__ QE,
                                                   const float* __restrict__ K,
                                                   const void* __restrict__ mask,
                                                   const float* __restrict__ nel,
                                                   const int* __restrict__ flag) {
    const int xt = blockIdx.x;       // 0..31
    const int h  = blockIdx.y;       // 0..7
    const int b  = blockIdx.z;       // 0..15
    const int x0 = xt * 32;
    const int tid = threadIdx.x;

    __shared__ float Qs[64][36];     // [d][xi]
    __shared__ float Kt[64][65];     // [yi][d]   (also reused as Ct[d][xi] at end)
    __shared__ float St[64][36];     // [yi][xi]

    const int maskInt = *flag;
    const uint8_t* m8  = (const uint8_t*)mask;
    const int*     m32 = (const int*)mask;

    const float* Qbase = QE + ((size_t)b * U_ + h * D_) * LX_;
    const float* Kbase = K  + ((size_t)b * U_ + h * D_) * LY_;

    // load Q tile: Qs[d][xi]
    #pragma unroll
    for (int e = 0; e < 8; ++e) {
        int idx = e * 256 + tid;
        int xi = idx & 31, d = idx >> 5;
        Qs[d][xi] = Qbase[(size_t)d * LX_ + x0 + xi];
    }

    // S-phase mapping: 4 xi x 2 yi per thread
    const int sx = tid & 7;          // xi = sx*4 + i
    const int sy = tid >> 3;         // yi = sy*2 + j
    const int xi0 = sx * 4;
    const int yi0 = sy * 2;
    // C-phase mapping: thread owns d = dc, xi = xg..xg+7
    const int dc = tid & 63;
    const int xg = (tid >> 6) * 8;

    float acc[8];
    #pragma unroll
    for (int i = 0; i < 8; ++i) acc[i] = 0.f;

    for (int y0 = 0; y0 < LY_; y0 += 64) {
        __syncthreads();   // previous iteration's readers of Kt/St done
        // load K tile transposed: Kt[yi][d] = K[d][y0+yi]
        #pragma unroll
        for (int e = 0; e < 16; ++e) {
            int idx = e * 256 + tid;
            int yi = idx & 63, d = idx >> 6;
            Kt[yi][d] = Kbase[(size_t)d * LY_ + y0 + yi];
        }
        __syncthreads();

        // ---- S phase: 4x2 microtile dot over d=64 ----
        {
            float s00 = 0.f, s01 = 0.f, s02 = 0.f, s03 = 0.f;
            float s10 = 0.f, s11 = 0.f, s12 = 0.f, s13 = 0.f;
            #pragma unroll 16
            for (int d = 0; d < 64; ++d) {
                float4 q4 = *(const float4*)&Qs[d][xi0];
                float k0 = Kt[yi0][d];
                float k1 = Kt[yi0 + 1][d];
                s00 += q4.x * k0; s01 += q4.y * k0; s02 += q4.z * k0; s03 += q4.w * k0;
                s10 += q4.x * k1; s11 += q4.y * k1; s12 += q4.z * k1; s13 += q4.w * k1;
            }
            const size_t mrow0 = ((size_t)b * LX_ + x0 + xi0) * LY_ + y0 + yi0;
            float v[8] = { s00, s01, s02, s03, s10, s11, s12, s13 };
            float r[8];
            #pragma unroll
            for (int j = 0; j < 2; ++j) {
                #pragma unroll
                for (int i = 0; i < 4; ++i) {
                    size_t mi = mrow0 + (size_t)i * LY_ + j;
                    bool mk = maskInt ? (m32[mi] != 0) : (m8[mi] != 0);
                    float s = v[j * 4 + i];
                    r[j * 4 + i] = mk ? fmaxf(s, 0.f) * 0.125f : 0.f;
                }
            }
            *(float4*)&St[yi0][xi0]     = make_float4(r[0], r[1], r[2], r[3]);
            *(float4*)&St[yi0 + 1][xi0] = make_float4(r[4], r[5], r[6], r[7]);
        }
        __syncthreads();

        // ---- C phase: acc[d=dc][xi=xg..xg+7] += S[xi][yi] * K[d][yi] ----
        #pragma unroll 16
        for (int yi = 0; yi < 64; ++yi) {
            float k = Kt[yi][dc];
            float4 sA = *(const float4*)&St[yi][xg];
            float4 sB = *(const float4*)&St[yi][xg + 4];
            acc[0] += sA.x * k; acc[1] += sA.y * k; acc[2] += sA.z * k; acc[3] += sA.w * k;
            acc[4] += sB.x * k; acc[5] += sB.y * k; acc[6] += sB.z * k; acc[7] += sB.w * k;
        }
    }

    // ---- epilogue: transpose C through LDS (reuse Kt as Ct[d][xi], stride 65) ----
    __syncthreads();
    float* Ct = &Kt[0][0];
    #pragma unroll
    for (int i = 0; i < 8; ++i) Ct[dc * 65 + xg + i] = acc[i];
    __syncthreads();

    const int xi = tid & 31;
    const int dg = tid >> 5;         // 0..7
    const float n = nel[(size_t)b * LX_ + x0 + xi];
    const float invn = 1.0f / n;
    float* Ebase = QE + ((size_t)b * U_ + h * D_) * LX_;
    #pragma unroll
    for (int dd = 0; dd < 8; ++dd) {
        int d = dg * 8 + dd;
        float c = Ct[d * 65 + xi];
        float e = 0.5f * (Qs[d][xi] + c * invn);
        Ebase[(size_t)d * LX_ + x0 + xi] = e;
    }
}

// ---------------------------------------------------------------------------
extern "C" void kernel_launch(void* const* d_in, const int* in_sizes, int n_in,
                              void* d_out, int out_size, void* d_ws, size_t ws_size,
                              hipStream_t stream) {
    const float* x    = (const float*)d_in[0];
    const float* y    = (const float*)d_in[1];
    const void*  mask = d_in[2];
    const float* wq   = (const float*)d_in[3];
    const float* wk   = (const float*)d_in[4];
    const float* wo   = (const float*)d_in[5];
    float* out = (float*)d_out;

    float* ws  = (float*)d_ws;
    float* Q   = ws;                               // B*U*LX = 8388608 floats (E in-place)
    float* K   = ws + (size_t)B_ * U_ * LX_;       // 8388608 floats
    float* nel = K  + (size_t)B_ * U_ * LY_;       // B*LX = 16384 floats
    int*   flag = (int*)(nel + (size_t)B_ * LX_);  // 1 int

    detect_kernel<<<1, 256, 0, stream>>>((const unsigned*)mask, flag);
    gemm512<<<dim3(LX_ / 64, U_ / 64, B_), 256, 0, stream>>>(wq, x, Q, LX_);
    gemm512<<<dim3(LY_ / 64, U_ / 64, B_), 256, 0, stream>>>(wk, y, K, LY_);
    nel_kernel<<<(B_ * LX_) / 4, 256, 0, stream>>>(mask, flag, nel);
    attn_kernel<<<dim3(LX_ / 32, H_, B_), 256, 0, stream>>>(Q, K, mask, nel, flag);
    gemm512<<<dim3(LX_ / 64, U_ / 64, B_), 256, 0, stream>>>(wo, Q /*E*/, out, LX_);
}

// Round 2
// 645.671 us; speedup vs baseline: 1.8944x; 1.8944x over previous
//
#include <hip/hip_runtime.h>
#include <stdint.h>
#include <stddef.h>

#define B_  16
#define U_  512
#define LX_ 1024
#define LY_ 1024
#define H_  8
#define D_  64

typedef unsigned short ushort_t;
typedef unsigned int   uint_t;
typedef __bf16 v8bf  __attribute__((ext_vector_type(8)));
typedef float  v16f  __attribute__((ext_vector_type(16)));

__device__ __forceinline__ ushort_t bf16u(float f) {
    uint_t u = __float_as_uint(f);
    uint_t r = (u + 0x7FFFu + ((u >> 16) & 1u)) >> 16;
    return (ushort_t)r;
}

// ---------------------------------------------------------------------------
// Detect mask element width: int32 (all first-1024 words <= 1) vs uint8.
// ---------------------------------------------------------------------------
__global__ void detect_kernel(const uint_t* __restrict__ mask, int* __restrict__ flag) {
    __shared__ int s;
    if (threadIdx.x == 0) s = 0;
    __syncthreads();
    int c = 0;
    for (int i = threadIdx.x; i < 1024; i += 256) c += (mask[i] <= 1u) ? 1 : 0;
    atomicAdd(&s, c);
    __syncthreads();
    if (threadIdx.x == 0) *flag = (s >= 1000) ? 1 : 0;
}

// ---------------------------------------------------------------------------
// n_el[b,x] = max(sum_y mask[b,x,y], 1) as float. One wave per row.
// ---------------------------------------------------------------------------
__global__ __launch_bounds__(256) void nel_kernel(const void* __restrict__ mask,
                                                  const int* __restrict__ flag,
                                                  float* __restrict__ nel) {
    int row  = blockIdx.x * 4 + (threadIdx.x >> 6);
    int lane = threadIdx.x & 63;
    int cnt = 0;
    if (*flag) {
        const int* m = (const int*)mask + (size_t)row * LY_;
        for (int i = lane; i < LY_; i += 64) cnt += (m[i] != 0) ? 1 : 0;
    } else {
        const uint8_t* m = (const uint8_t*)mask + (size_t)row * LY_;
        uint4 v = ((const uint4*)m)[lane];
        uint_t a = (v.x & 0x01010101u) + (v.y & 0x01010101u)
                 + (v.z & 0x01010101u) + (v.w & 0x01010101u);
        cnt = (int)((a * 0x01010101u) >> 24);
    }
    for (int off = 32; off > 0; off >>= 1) cnt += __shfl_down(cnt, off, 64);
    if (lane == 0) nel[row] = (float)(cnt > 0 ? cnt : 1);
}

// ---------------------------------------------------------------------------
// maskBits[b][x][y/32] : bit y set iff mask[b,x,y]!=0.  One wave per row,
// ballot over 64 consecutive y per step (coalesced byte loads).
// ---------------------------------------------------------------------------
__global__ __launch_bounds__(256) void maskbits_kernel(const void* __restrict__ mask,
                                                       const int* __restrict__ flag,
                                                       uint_t* __restrict__ mb) {
    int row  = blockIdx.x * 4 + (threadIdx.x >> 6);   // b*1024 + x
    int lane = threadIdx.x & 63;
    const int isInt = *flag;
    const uint8_t* m8  = (const uint8_t*)mask + (size_t)row * LY_;
    const int*     m32 = (const int*)mask + (size_t)row * LY_;
    for (int yg = 0; yg < LY_ / 64; ++yg) {
        int y = yg * 64 + lane;
        bool p = isInt ? (m32[y] != 0) : (m8[y] != 0);
        unsigned long long bal = __ballot(p);
        if (lane == 0) {
            mb[(size_t)row * 32 + yg * 2]     = (uint_t)bal;
            mb[(size_t)row * 32 + yg * 2 + 1] = (uint_t)(bal >> 32);
        }
    }
}

// ---------------------------------------------------------------------------
// fp32 GEMM  Out[b] = W(512x512) @ X[b](512xL). 64x64 tile, bk=16, 4x4 micro.
// ---------------------------------------------------------------------------
__global__ __launch_bounds__(256) void gemm512(const float* __restrict__ W,
                                               const float* __restrict__ X,
                                               float* __restrict__ Out, int L) {
    const int l0 = blockIdx.x * 64;
    const int o0 = blockIdx.y * 64;
    const int b  = blockIdx.z;
    const float* Xb = X + (size_t)b * U_ * L;
    float*       Ob = Out + (size_t)b * U_ * L;

    __shared__ float Ws[16][68];
    __shared__ float Xs[16][68];

    const int tid = threadIdx.x;
    const int tx = tid & 15;
    const int ty = tid >> 4;

    float acc[4][4];
    #pragma unroll
    for (int i = 0; i < 4; ++i)
        #pragma unroll
        for (int j = 0; j < 4; ++j) acc[i][j] = 0.f;

    for (int u0 = 0; u0 < U_; u0 += 16) {
        {
            int o  = tid >> 2;
            int j4 = (tid & 3) * 4;
            float4 wv = *(const float4*)&W[(size_t)(o0 + o) * U_ + u0 + j4];
            Ws[j4 + 0][o] = wv.x; Ws[j4 + 1][o] = wv.y;
            Ws[j4 + 2][o] = wv.z; Ws[j4 + 3][o] = wv.w;
        }
        {
            int j  = tid >> 4;
            int i4 = (tid & 15) * 4;
            *(float4*)&Xs[j][i4] = *(const float4*)&Xb[(size_t)(u0 + j) * L + l0 + i4];
        }
        __syncthreads();
        #pragma unroll
        for (int u = 0; u < 16; ++u) {
            float4 wv = *(const float4*)&Ws[u][ty * 4];
            float4 xv = *(const float4*)&Xs[u][tx * 4];
            acc[0][0] += wv.x * xv.x; acc[0][1] += wv.x * xv.y; acc[0][2] += wv.x * xv.z; acc[0][3] += wv.x * xv.w;
            acc[1][0] += wv.y * xv.x; acc[1][1] += wv.y * xv.y; acc[1][2] += wv.y * xv.z; acc[1][3] += wv.y * xv.w;
            acc[2][0] += wv.z * xv.x; acc[2][1] += wv.z * xv.y; acc[2][2] += wv.z * xv.z; acc[2][3] += wv.z * xv.w;
            acc[3][0] += wv.w * xv.x; acc[3][1] += wv.w * xv.y; acc[3][2] += wv.w * xv.z; acc[3][3] += wv.w * xv.w;
        }
        __syncthreads();
    }
    #pragma unroll
    for (int i = 0; i < 4; ++i) {
        float4 v = make_float4(acc[i][0], acc[i][1], acc[i][2], acc[i][3]);
        *(float4*)&Ob[(size_t)(o0 + ty * 4 + i) * L + l0 + tx * 4] = v;
    }
}

// ---------------------------------------------------------------------------
// Same GEMM, epilogue writes bf16 (natural [b][u][y] layout) -> Kg_a.
// ---------------------------------------------------------------------------
__global__ __launch_bounds__(256) void gemm512_kbf16(const float* __restrict__ W,
                                                     const float* __restrict__ X,
                                                     ushort_t* __restrict__ Ko) {
    const int l0 = blockIdx.x * 64;
    const int o0 = blockIdx.y * 64;
    const int b  = blockIdx.z;
    const float* Xb = X + (size_t)b * U_ * LY_;

    __shared__ float Ws[16][68];
    __shared__ float Xs[16][68];

    const int tid = threadIdx.x;
    const int tx = tid & 15;
    const int ty = tid >> 4;

    float acc[4][4];
    #pragma unroll
    for (int i = 0; i < 4; ++i)
        #pragma unroll
        for (int j = 0; j < 4; ++j) acc[i][j] = 0.f;

    for (int u0 = 0; u0 < U_; u0 += 16) {
        {
            int o  = tid >> 2;
            int j4 = (tid & 3) * 4;
            float4 wv = *(const float4*)&W[(size_t)(o0 + o) * U_ + u0 + j4];
            Ws[j4 + 0][o] = wv.x; Ws[j4 + 1][o] = wv.y;
            Ws[j4 + 2][o] = wv.z; Ws[j4 + 3][o] = wv.w;
        }
        {
            int j  = tid >> 4;
            int i4 = (tid & 15) * 4;
            *(float4*)&Xs[j][i4] = *(const float4*)&Xb[(size_t)(u0 + j) * LY_ + l0 + i4];
        }
        __syncthreads();
        #pragma unroll
        for (int u = 0; u < 16; ++u) {
            float4 wv = *(const float4*)&Ws[u][ty * 4];
            float4 xv = *(const float4*)&Xs[u][tx * 4];
            acc[0][0] += wv.x * xv.x; acc[0][1] += wv.x * xv.y; acc[0][2] += wv.x * xv.z; acc[0][3] += wv.x * xv.w;
            acc[1][0] += wv.y * xv.x; acc[1][1] += wv.y * xv.y; acc[1][2] += wv.y * xv.z; acc[1][3] += wv.y * xv.w;
            acc[2][0] += wv.z * xv.x; acc[2][1] += wv.z * xv.y; acc[2][2] += wv.z * xv.z; acc[2][3] += wv.z * xv.w;
            acc[3][0] += wv.w * xv.x; acc[3][1] += wv.w * xv.y; acc[3][2] += wv.w * xv.z; acc[3][3] += wv.w * xv.w;
        }
        __syncthreads();
    }
    #pragma unroll
    for (int i = 0; i < 4; ++i) {
        ushort4 pk;
        pk.x = bf16u(acc[i][0]); pk.y = bf16u(acc[i][1]);
        pk.z = bf16u(acc[i][2]); pk.w = bf16u(acc[i][3]);
        *(ushort4*)&Ko[((size_t)(b * U_ + o0 + ty * 4 + i) << 10) + l0 + tx * 4] = pk;
    }
}

// ---------------------------------------------------------------------------
// Kg_a[b][u=h*64+d][y] bf16  ->  Kg_b[b][h][y][d] bf16  (64x64 LDS transpose)
// ---------------------------------------------------------------------------
__global__ __launch_bounds__(256) void ktranspose_kernel(const ushort_t* __restrict__ Ka,
                                                         ushort_t* __restrict__ Kb) {
    const int y0 = blockIdx.x * 64;
    const int h  = blockIdx.y;
    const int b  = blockIdx.z;
    __shared__ ushort_t T[64][72];
    const int tid = threadIdx.x;

    #pragma unroll
    for (int e = 0; e < 2; ++e) {
        int idx = e * 256 + tid;
        int d = idx >> 3, c = idx & 7;
        uint4 v = *(const uint4*)&Ka[((size_t)(b * U_ + h * D_ + d) << 10) + y0 + c * 8];
        *(uint4*)&T[d][c * 8] = v;
    }
    __syncthreads();
    #pragma unroll
    for (int e = 0; e < 2; ++e) {
        int idx = e * 256 + tid;
        int yy = idx >> 3, dc = idx & 7;
        ushort_t tmp[8];
        #pragma unroll
        for (int j = 0; j < 8; ++j) tmp[j] = T[dc * 8 + j][yy];
        *(uint4*)&Kb[(((size_t)(b * H_ + h) << 10) + y0 + yy) * D_ + dc * 8] = *(uint4*)tmp;
    }
}

// ---------------------------------------------------------------------------
// Fused bf16-MFMA attention.
// grid (Lx/128, H, B), 256 threads (4 waves). LDS 48 KB, xor-chunk-swizzled.
//   S^T[y][x] = mfma(Kb[y][d], Qt[x][d])    (32x32x16, k=d)
//   P = mask ? relu(S)*0.125 : 0  -> St[x][y] bf16
//   C[d][x]  += mfma(Ka[d][y], St[x][y])    (k=y, accumulated over y-tiles)
//   E[d][x] = 0.5*(Q + C/nel)  written in place over Q (fp32, in d_out)
// ---------------------------------------------------------------------------
__global__ __launch_bounds__(256) void attn_mfma(float* __restrict__ QE,
                                                 const ushort_t* __restrict__ Ka_g,
                                                 const ushort_t* __restrict__ Kb_g,
                                                 const uint_t* __restrict__ mbits,
                                                 const float* __restrict__ nel) {
    const int tid = threadIdx.x;
    const int x0g = blockIdx.x * 128;
    const int h = blockIdx.y, b = blockIdx.z;

    __shared__ __align__(16) ushort_t Qt[128 * 64];
    __shared__ __align__(16) ushort_t Kb[64 * 64];
    __shared__ __align__(16) ushort_t Ka[64 * 64];
    __shared__ __align__(16) ushort_t St[128 * 64];

    const int w    = tid >> 6;
    const int lane = tid & 63;
    const int lo   = lane & 31;
    const int hi   = lane >> 5;

    // ---- stage Qt[x][d] (swizzled) from fp32 Q ----
    const float* Qbase = QE + (((size_t)(b * U_ + h * D_)) << 10) + x0g;
    #pragma unroll
    for (int e = 0; e < 8; ++e) {
        int idx = e * 256 + tid;
        int d = idx >> 5, xg4 = (idx & 31) * 4;
        float4 q = *(const float4*)&Qbase[((size_t)d << 10) + xg4];
        #pragma unroll
        for (int j = 0; j < 4; ++j) {
            int row = xg4 + j;
            Qt[row * 64 + ((((d >> 3) ^ (row & 7)) << 3) | (d & 7))] = bf16u(((const float*)&q)[j]);
        }
    }

    v16f accC0, accC1;
    #pragma unroll
    for (int i = 0; i < 16; ++i) { accC0[i] = 0.f; accC1[i] = 0.f; }

    const int yw  = w & 1;           // S: y-sub;  C: d-sub = yw*32
    const int xws = (w >> 1) * 64;   // x-subs xws + {0,32}

    const ushort_t* KaBase = Ka_g + (((size_t)(b * U_ + h * D_)) << 10);
    const ushort_t* KbBase = Kb_g + (((size_t)(b * H_ + h)) << 10) * D_;

    for (int y0 = 0; y0 < LY_; y0 += 64) {
        __syncthreads();
        // ---- stage Kb[y][d], Ka[d][y] (both 64x64 bf16, swizzled) ----
        #pragma unroll
        for (int e = 0; e < 2; ++e) {
            int idx = e * 256 + tid;           // 0..511
            int row = idx >> 3, c = idx & 7;
            uint4 vb = *(const uint4*)&KbBase[((size_t)(y0 + row) << 6) + c * 8];
            *(uint4*)&Kb[row * 64 + ((c ^ (row & 7)) << 3)] = vb;
            uint4 va = *(const uint4*)&KaBase[((size_t)row << 10) + y0 + c * 8];
            *(uint4*)&Ka[row * 64 + ((c ^ (row & 7)) << 3)] = va;
        }
        __syncthreads();

        // ---- S-phase: S^T = Kb * Qt^T ----
        v16f s0, s1;
        #pragma unroll
        for (int i = 0; i < 16; ++i) { s0[i] = 0.f; s1[i] = 0.f; }
        #pragma unroll
        for (int kt = 0; kt < 4; ++kt) {
            int ch = kt * 2 + hi;
            int rowA  = yw * 32 + lo;
            int rowB0 = xws + lo;
            int rowB1 = xws + 32 + lo;
            v8bf a  = *(v8bf*)&Kb[rowA * 64 + ((ch ^ (rowA & 7)) << 3)];
            v8bf b0 = *(v8bf*)&Qt[rowB0 * 64 + ((ch ^ (rowB0 & 7)) << 3)];
            v8bf b1 = *(v8bf*)&Qt[rowB1 * 64 + ((ch ^ (rowB1 & 7)) << 3)];
            s0 = __builtin_amdgcn_mfma_f32_32x32x16_bf16(a, b0, s0, 0, 0, 0);
            s1 = __builtin_amdgcn_mfma_f32_32x32x16_bf16(a, b1, s1, 0, 0, 0);
        }
        // ---- mask + relu + scale, write St[x][y] bf16 ----
        #pragma unroll
        for (int i = 0; i < 2; ++i) {
            v16f s = i ? s1 : s0;
            int xl = xws + i * 32 + lo;
            uint2 mm = *(const uint2*)&mbits[((size_t)((b << 10) + x0g + xl)) * 32 + (y0 >> 5)];
            uint_t wbits = yw ? mm.y : mm.x;
            #pragma unroll
            for (int g = 0; g < 4; ++g) {
                ushort4 pk;
                #pragma unroll
                for (int q = 0; q < 4; ++q) {
                    int rowmap = q + g * 8 + 4 * hi;
                    float v = s[g * 4 + q];
                    float p = ((wbits >> rowmap) & 1u) ? fmaxf(v, 0.f) * 0.125f : 0.f;
                    ((ushort_t*)&pk)[q] = bf16u(p);
                }
                int yb = yw * 32 + g * 8 + 4 * hi;
                *(ushort4*)&St[xl * 64 + (((yb >> 3) ^ (xl & 7)) << 3) + (yb & 7)] = pk;
            }
        }
        __syncthreads();

        // ---- C-phase: C[d][x] += Ka * St^T ----
        #pragma unroll
        for (int kt = 0; kt < 4; ++kt) {
            int ch = kt * 2 + hi;
            int rowA  = yw * 32 + lo;       // d rows
            int rowB0 = xws + lo;
            int rowB1 = xws + 32 + lo;
            v8bf a  = *(v8bf*)&Ka[rowA * 64 + ((ch ^ (rowA & 7)) << 3)];
            v8bf b0 = *(v8bf*)&St[rowB0 * 64 + ((ch ^ (rowB0 & 7)) << 3)];
            v8bf b1 = *(v8bf*)&St[rowB1 * 64 + ((ch ^ (rowB1 & 7)) << 3)];
            accC0 = __builtin_amdgcn_mfma_f32_32x32x16_bf16(a, b0, accC0, 0, 0, 0);
            accC1 = __builtin_amdgcn_mfma_f32_32x32x16_bf16(a, b1, accC1, 0, 0, 0);
        }
    }

    // ---- epilogue: E = 0.5*(Q + C/nel), in place ----
    #pragma unroll
    for (int i = 0; i < 2; ++i) {
        v16f c = i ? accC1 : accC0;
        int xl = xws + i * 32 + lo;
        int xg = x0g + xl;
        float invn = 1.0f / nel[(b << 10) + xg];
        #pragma unroll
        for (int r = 0; r < 16; ++r) {
            int d = yw * 32 + (r & 3) + 8 * (r >> 2) + 4 * hi;
            size_t addr = (((size_t)(b * U_ + h * D_ + d)) << 10) + xg;
            QE[addr] = 0.5f * (QE[addr] + c[r] * invn);
        }
    }
}

// ---------------------------------------------------------------------------
extern "C" void kernel_launch(void* const* d_in, const int* in_sizes, int n_in,
                              void* d_out, int out_size, void* d_ws, size_t ws_size,
                              hipStream_t stream) {
    const float* x    = (const float*)d_in[0];
    const float* y    = (const float*)d_in[1];
    const void*  mask = d_in[2];
    const float* wq   = (const float*)d_in[3];
    const float* wk   = (const float*)d_in[4];
    const float* wo   = (const float*)d_in[5];
    float* out = (float*)d_out;

    // workspace layout (bytes):
    //   [0, 16777216)            Kg_a  bf16  (later reused as outTmp low half)
    //   [16777216, 33554432)     Kg_b  bf16  (later reused as outTmp high half)
    //   [33554432, 35651584)     maskBits u32
    //   [35651584, 35717120)     nel   f32
    //   [35717120, ...)          flag  int
    char* wsb = (char*)d_ws;
    ushort_t* Kg_a  = (ushort_t*)(wsb);
    ushort_t* Kg_b  = (ushort_t*)(wsb + 16777216);
    uint_t*   mbits = (uint_t*)(wsb + 33554432);
    float*    nel   = (float*)(wsb + 35651584);
    int*      flag  = (int*)(wsb + 35717120);
    float*    outTmp = (float*)(wsb);           // 33.5 MB, overlaps Kg_a/Kg_b (dead by then)
    float*    Q = (float*)d_out;                // Q/E lives in d_out until final GEMM

    detect_kernel<<<1, 256, 0, stream>>>((const uint_t*)mask, flag);
    nel_kernel<<<(B_ * LX_) / 4, 256, 0, stream>>>(mask, flag, nel);
    maskbits_kernel<<<(B_ * LX_) / 4, 256, 0, stream>>>(mask, flag, mbits);
    gemm512<<<dim3(LX_ / 64, U_ / 64, B_), 256, 0, stream>>>(wq, x, Q, LX_);
    gemm512_kbf16<<<dim3(LY_ / 64, U_ / 64, B_), 256, 0, stream>>>(wk, y, Kg_a);
    ktranspose_kernel<<<dim3(LY_ / 64, H_, B_), 256, 0, stream>>>(Kg_a, Kg_b);
    attn_mfma<<<dim3(LX_ / 128, H_, B_), 256, 0, stream>>>(Q, Kg_a, Kg_b, mbits, nel);
    gemm512<<<dim3(LX_ / 64, U_ / 64, B_), 256, 0, stream>>>(wo, Q /*E*/, outTmp, LX_);
    hipMemcpyAsync(out, outTmp, (size_t)out_size * sizeof(float),
                   hipMemcpyDeviceToDevice, stream);
}

// Round 3
// 347.847 us; speedup vs baseline: 3.5164x; 1.8562x over previous
//
#include <hip/hip_runtime.h>
#include <stdint.h>
#include <stddef.h>

#define B_  16
#define U_  512
#define LX_ 1024
#define LY_ 1024
#define H_  8
#define D_  64

typedef unsigned short ushort_t;
typedef unsigned int   uint_t;
typedef __bf16 v8bf  __attribute__((ext_vector_type(8)));
typedef float  v16f  __attribute__((ext_vector_type(16)));

__device__ __forceinline__ ushort_t bf16u(float f) {
    uint_t u = __float_as_uint(f);
    uint_t r = (u + 0x7FFFu + ((u >> 16) & 1u)) >> 16;
    return (ushort_t)r;
}
__device__ __forceinline__ float bfu2f(ushort_t u) {
    return __uint_as_float(((uint_t)u) << 16);
}
// async global->LDS, 16B per lane. LDS dest is wave-uniform base + lane*16,
// so any swizzle must be applied to the GLOBAL source chunk, not the LDS addr.
__device__ __forceinline__ void gload16(const void* g, void* l) {
    auto gp = (const __attribute__((address_space(1))) uint32_t*)(uintptr_t)g;
    auto lp = (__attribute__((address_space(3))) uint32_t*)(uintptr_t)l;
    __builtin_amdgcn_global_load_lds(gp, lp, 16, 0, 0);
}

// ---------------------------------------------------------------------------
// Detect mask element width: int32 (all first-1024 words <= 1) vs uint8.
// ---------------------------------------------------------------------------
__global__ void detect_kernel(const uint_t* __restrict__ mask, int* __restrict__ flag) {
    __shared__ int s;
    if (threadIdx.x == 0) s = 0;
    __syncthreads();
    int c = 0;
    for (int i = threadIdx.x; i < 1024; i += 256) c += (mask[i] <= 1u) ? 1 : 0;
    atomicAdd(&s, c);
    __syncthreads();
    if (threadIdx.x == 0) *flag = (s >= 1000) ? 1 : 0;
}

// ---------------------------------------------------------------------------
// n_el[b,x] = max(sum_y mask[b,x,y], 1) as float. One wave per row.
// ---------------------------------------------------------------------------
__global__ __launch_bounds__(256) void nel_kernel(const void* __restrict__ mask,
                                                  const int* __restrict__ flag,
                                                  float* __restrict__ nel) {
    int row  = blockIdx.x * 4 + (threadIdx.x >> 6);
    int lane = threadIdx.x & 63;
    int cnt = 0;
    if (*flag) {
        const int* m = (const int*)mask + (size_t)row * LY_;
        for (int i = lane; i < LY_; i += 64) cnt += (m[i] != 0) ? 1 : 0;
    } else {
        const uint8_t* m = (const uint8_t*)mask + (size_t)row * LY_;
        uint4 v = ((const uint4*)m)[lane];
        uint_t a = (v.x & 0x01010101u) + (v.y & 0x01010101u)
                 + (v.z & 0x01010101u) + (v.w & 0x01010101u);
        cnt = (int)((a * 0x01010101u) >> 24);
    }
    for (int off = 32; off > 0; off >>= 1) cnt += __shfl_down(cnt, off, 64);
    if (lane == 0) nel[row] = (float)(cnt > 0 ? cnt : 1);
}

// ---------------------------------------------------------------------------
// maskBits[b][x][y/32] : bit y set iff mask[b,x,y]!=0.
// ---------------------------------------------------------------------------
__global__ __launch_bounds__(256) void maskbits_kernel(const void* __restrict__ mask,
                                                       const int* __restrict__ flag,
                                                       uint_t* __restrict__ mb) {
    int row  = blockIdx.x * 4 + (threadIdx.x >> 6);   // b*1024 + x
    int lane = threadIdx.x & 63;
    const int isInt = *flag;
    const uint8_t* m8  = (const uint8_t*)mask + (size_t)row * LY_;
    const int*     m32 = (const int*)mask + (size_t)row * LY_;
    for (int yg = 0; yg < LY_ / 64; ++yg) {
        int y = yg * 64 + lane;
        bool p = isInt ? (m32[y] != 0) : (m8[y] != 0);
        unsigned long long bal = __ballot(p);
        if (lane == 0) {
            mb[(size_t)row * 32 + yg * 2]     = (uint_t)bal;
            mb[(size_t)row * 32 + yg * 2 + 1] = (uint_t)(bal >> 32);
        }
    }
}

// ---------------------------------------------------------------------------
// fp32 -> bf16 flat cast (for the 512x512 weights)
// ---------------------------------------------------------------------------
__global__ __launch_bounds__(256) void cast_bf16(const float* __restrict__ src,
                                                 ushort_t* __restrict__ dst) {
    int i = (blockIdx.x * 256 + threadIdx.x) * 4;
    float4 v = *(const float4*)&src[i];
    ushort4 p;
    p.x = bf16u(v.x); p.y = bf16u(v.y); p.z = bf16u(v.z); p.w = bf16u(v.w);
    *(ushort4*)&dst[i] = p;
}

// ---------------------------------------------------------------------------
// x[b][u][l] fp32 -> xT[b][l][u] bf16, 64x64 LDS tiles.
// grid (L/64, U/64, B)
// ---------------------------------------------------------------------------
__global__ __launch_bounds__(256) void castT_kernel(const float* __restrict__ X,
                                                    ushort_t* __restrict__ XT) {
    const int l0 = blockIdx.x * 64;
    const int u0 = blockIdx.y * 64;
    const int b  = blockIdx.z;
    __shared__ ushort_t T[64][72];
    const int tid = threadIdx.x;
    #pragma unroll
    for (int e = 0; e < 4; ++e) {
        int ci = e * 256 + tid;            // 0..1023 float4s
        int r = ci >> 4, c4 = (ci & 15) * 4;
        float4 v = *(const float4*)&X[((size_t)(b * U_ + u0 + r) << 10) + l0 + c4];
        T[r][c4 + 0] = bf16u(v.x); T[r][c4 + 1] = bf16u(v.y);
        T[r][c4 + 2] = bf16u(v.z); T[r][c4 + 3] = bf16u(v.w);
    }
    __syncthreads();
    #pragma unroll
    for (int e = 0; e < 2; ++e) {
        int ci = e * 256 + tid;            // 0..511 chunks of 8
        int lr = ci >> 3, cc = ci & 7;
        ushort_t tmp[8];
        #pragma unroll
        for (int j = 0; j < 8; ++j) tmp[j] = T[cc * 8 + j][lr];
        *(uint4*)&XT[((size_t)((b << 10) + l0 + lr)) * U_ + u0 + cc * 8] = *(uint4*)tmp;
    }
}

// ---------------------------------------------------------------------------
// bf16 MFMA GEMM: Out[b][m][n] = sum_k A[m][k] * Bm[b][n][k]
// A = 512x512 weight (shared over batch), Bm = [b][1024][512].
// 128x128 tile, BK=64, global_load_lds staging w/ source-xor swizzle.
// OUTF32=0: bf16 out; OUTF32=1: fp32 out.
// ---------------------------------------------------------------------------
template <int OUTF32>
__global__ __launch_bounds__(256) void gemm_mfma(const ushort_t* __restrict__ A,
                                                 const ushort_t* __restrict__ Bm,
                                                 void* __restrict__ Out) {
    const int n0 = blockIdx.x * 128;
    const int m0 = blockIdx.y * 128;
    const int b  = blockIdx.z;
    __shared__ __align__(16) ushort_t As[128 * 64];
    __shared__ __align__(16) ushort_t Bs[128 * 64];
    const int tid = threadIdx.x;
    const ushort_t* Bb = Bm + ((size_t)b << 10) * U_;

    const int w = tid >> 6, lane = tid & 63, lo = lane & 31, hi = lane >> 5;
    const int wm = (w >> 1) * 64, wn = (w & 1) * 64;

    v16f acc00, acc01, acc10, acc11;
    #pragma unroll
    for (int i = 0; i < 16; ++i) { acc00[i] = 0.f; acc01[i] = 0.f; acc10[i] = 0.f; acc11[i] = 0.f; }

    for (int kk = 0; kk < 8; ++kk) {
        const int k0 = kk * 64;
        #pragma unroll
        for (int e = 0; e < 4; ++e) {
            int ci = e * 256 + tid;          // 0..1023 16B chunks
            int r = ci >> 3, c = ci & 7;
            int g = (c ^ (r & 7)) << 3;      // swizzle on SOURCE chunk
            gload16(&A[(size_t)(m0 + r) * U_ + k0 + g], &As[ci * 8]);
            gload16(&Bb[(size_t)(n0 + r) * U_ + k0 + g], &Bs[ci * 8]);
        }
        __syncthreads();
        #pragma unroll
        for (int ks = 0; ks < 4; ++ks) {
            int ch = ks * 2 + hi;
            int rA0 = wm + lo, rA1 = wm + 32 + lo;
            int rB0 = wn + lo, rB1 = wn + 32 + lo;
            v8bf a0 = *(v8bf*)&As[rA0 * 64 + ((ch ^ (rA0 & 7)) << 3)];
            v8bf a1 = *(v8bf*)&As[rA1 * 64 + ((ch ^ (rA1 & 7)) << 3)];
            v8bf b0 = *(v8bf*)&Bs[rB0 * 64 + ((ch ^ (rB0 & 7)) << 3)];
            v8bf b1 = *(v8bf*)&Bs[rB1 * 64 + ((ch ^ (rB1 & 7)) << 3)];
            acc00 = __builtin_amdgcn_mfma_f32_32x32x16_bf16(a0, b0, acc00, 0, 0, 0);
            acc01 = __builtin_amdgcn_mfma_f32_32x32x16_bf16(a0, b1, acc01, 0, 0, 0);
            acc10 = __builtin_amdgcn_mfma_f32_32x32x16_bf16(a1, b0, acc10, 0, 0, 0);
            acc11 = __builtin_amdgcn_mfma_f32_32x32x16_bf16(a1, b1, acc11, 0, 0, 0);
        }
        __syncthreads();
    }

    #pragma unroll
    for (int mi = 0; mi < 2; ++mi) {
        #pragma unroll
        for (int nj = 0; nj < 2; ++nj) {
            v16f c = mi ? (nj ? acc11 : acc10) : (nj ? acc01 : acc00);
            int n = n0 + wn + nj * 32 + lo;
            #pragma unroll
            for (int r = 0; r < 16; ++r) {
                int m = m0 + wm + mi * 32 + (r & 3) + 8 * (r >> 2) + 4 * hi;
                size_t addr = ((size_t)(b * U_ + m) << 10) + n;
                if (OUTF32) ((float*)Out)[addr] = c[r];
                else        ((ushort_t*)Out)[addr] = bf16u(c[r]);
            }
        }
    }
}

// ---------------------------------------------------------------------------
// Ka[b][u=h*64+d][y] bf16 -> Kb[b][h][y][d] bf16 (64x64 LDS transpose)
// ---------------------------------------------------------------------------
__global__ __launch_bounds__(256) void ktranspose_kernel(const ushort_t* __restrict__ Ka,
                                                         ushort_t* __restrict__ Kb) {
    const int y0 = blockIdx.x * 64;
    const int h  = blockIdx.y;
    const int b  = blockIdx.z;
    __shared__ ushort_t T[64][72];
    const int tid = threadIdx.x;

    #pragma unroll
    for (int e = 0; e < 2; ++e) {
        int idx = e * 256 + tid;
        int d = idx >> 3, c = idx & 7;
        uint4 v = *(const uint4*)&Ka[((size_t)(b * U_ + h * D_ + d) << 10) + y0 + c * 8];
        *(uint4*)&T[d][c * 8] = v;
    }
    __syncthreads();
    #pragma unroll
    for (int e = 0; e < 2; ++e) {
        int idx = e * 256 + tid;
        int yy = idx >> 3, dc = idx & 7;
        ushort_t tmp[8];
        #pragma unroll
        for (int j = 0; j < 8; ++j) tmp[j] = T[dc * 8 + j][yy];
        *(uint4*)&Kb[(((size_t)(b * H_ + h) << 10) + y0 + yy) * D_ + dc * 8] = *(uint4*)tmp;
    }
}

// ---------------------------------------------------------------------------
// Fused bf16-MFMA attention. Q bf16 in, ET[b][x][u] bf16 out.
// grid (Lx/128, H, B), 256 threads. LDS 48 KB xor-swizzled.
// ---------------------------------------------------------------------------
__global__ __launch_bounds__(256) void attn_mfma(const ushort_t* __restrict__ Qg,
                                                 const ushort_t* __restrict__ Ka_g,
                                                 const ushort_t* __restrict__ Kb_g,
                                                 const uint_t* __restrict__ mbits,
                                                 const float* __restrict__ nel,
                                                 ushort_t* __restrict__ ETg) {
    const int tid = threadIdx.x;
    const int x0g = blockIdx.x * 128;
    const int h = blockIdx.y, b = blockIdx.z;

    __shared__ __align__(16) ushort_t Qt[128 * 64];
    __shared__ __align__(16) ushort_t Kb[64 * 64];
    __shared__ __align__(16) ushort_t Ka[64 * 64];
    __shared__ __align__(16) ushort_t St[128 * 64];

    const int w    = tid >> 6;
    const int lane = tid & 63;
    const int lo   = lane & 31;
    const int hi   = lane >> 5;

    // ---- stage Qt[x][d] (swizzled) from bf16 Q[d][x] ----
    const ushort_t* Qbase = Qg + (((size_t)(b * U_ + h * D_)) << 10) + x0g;
    #pragma unroll
    for (int e = 0; e < 4; ++e) {
        int idx = e * 256 + tid;            // 0..1023 chunks of 8 x
        int d = idx >> 4, x8 = (idx & 15) * 8;
        ushort_t vv[8];
        *(uint4*)vv = *(const uint4*)&Qbase[((size_t)d << 10) + x8];
        #pragma unroll
        for (int j = 0; j < 8; ++j) {
            int row = x8 + j;
            Qt[row * 64 + ((((d >> 3) ^ (row & 7)) << 3) | (d & 7))] = vv[j];
        }
    }

    v16f accC0, accC1;
    #pragma unroll
    for (int i = 0; i < 16; ++i) { accC0[i] = 0.f; accC1[i] = 0.f; }

    const int yw  = w & 1;           // S: y-sub;  C: d-sub = yw*32
    const int xws = (w >> 1) * 64;   // x-subs xws + {0,32}

    const ushort_t* KaBase = Ka_g + (((size_t)(b * U_ + h * D_)) << 10);
    const ushort_t* KbBase = Kb_g + (((size_t)(b * H_ + h)) << 10) * D_;

    for (int y0 = 0; y0 < LY_; y0 += 64) {
        __syncthreads();
        // ---- stage Kb[y][d], Ka[d][y] (64x64 bf16, swizzled) ----
        #pragma unroll
        for (int e = 0; e < 2; ++e) {
            int idx = e * 256 + tid;
            int row = idx >> 3, c = idx & 7;
            uint4 vb = *(const uint4*)&KbBase[((size_t)(y0 + row) << 6) + c * 8];
            *(uint4*)&Kb[row * 64 + ((c ^ (row & 7)) << 3)] = vb;
            uint4 va = *(const uint4*)&KaBase[((size_t)row << 10) + y0 + c * 8];
            *(uint4*)&Ka[row * 64 + ((c ^ (row & 7)) << 3)] = va;
        }
        __syncthreads();

        // ---- S-phase: S^T = Kb * Qt^T ----
        v16f s0, s1;
        #pragma unroll
        for (int i = 0; i < 16; ++i) { s0[i] = 0.f; s1[i] = 0.f; }
        #pragma unroll
        for (int kt = 0; kt < 4; ++kt) {
            int ch = kt * 2 + hi;
            int rowA  = yw * 32 + lo;
            int rowB0 = xws + lo;
            int rowB1 = xws + 32 + lo;
            v8bf a  = *(v8bf*)&Kb[rowA * 64 + ((ch ^ (rowA & 7)) << 3)];
            v8bf b0 = *(v8bf*)&Qt[rowB0 * 64 + ((ch ^ (rowB0 & 7)) << 3)];
            v8bf b1 = *(v8bf*)&Qt[rowB1 * 64 + ((ch ^ (rowB1 & 7)) << 3)];
            s0 = __builtin_amdgcn_mfma_f32_32x32x16_bf16(a, b0, s0, 0, 0, 0);
            s1 = __builtin_amdgcn_mfma_f32_32x32x16_bf16(a, b1, s1, 0, 0, 0);
        }
        // ---- mask + relu + scale, write St[x][y] bf16 ----
        #pragma unroll
        for (int i = 0; i < 2; ++i) {
            v16f s = i ? s1 : s0;
            int xl = xws + i * 32 + lo;
            uint2 mm = *(const uint2*)&mbits[((size_t)((b << 10) + x0g + xl)) * 32 + (y0 >> 5)];
            uint_t wbits = yw ? mm.y : mm.x;
            #pragma unroll
            for (int g = 0; g < 4; ++g) {
                ushort4 pk;
                #pragma unroll
                for (int q = 0; q < 4; ++q) {
                    int rowmap = q + g * 8 + 4 * hi;
                    float v = s[g * 4 + q];
                    float p = ((wbits >> rowmap) & 1u) ? fmaxf(v, 0.f) * 0.125f : 0.f;
                    ((ushort_t*)&pk)[q] = bf16u(p);
                }
                int yb = yw * 32 + g * 8 + 4 * hi;
                *(ushort4*)&St[xl * 64 + (((yb >> 3) ^ (xl & 7)) << 3) + (yb & 7)] = pk;
            }
        }
        __syncthreads();

        // ---- C-phase: C[d][x] += Ka * St^T ----
        #pragma unroll
        for (int kt = 0; kt < 4; ++kt) {
            int ch = kt * 2 + hi;
            int rowA  = yw * 32 + lo;
            int rowB0 = xws + lo;
            int rowB1 = xws + 32 + lo;
            v8bf a  = *(v8bf*)&Ka[rowA * 64 + ((ch ^ (rowA & 7)) << 3)];
            v8bf b0 = *(v8bf*)&St[rowB0 * 64 + ((ch ^ (rowB0 & 7)) << 3)];
            v8bf b1 = *(v8bf*)&St[rowB1 * 64 + ((ch ^ (rowB1 & 7)) << 3)];
            accC0 = __builtin_amdgcn_mfma_f32_32x32x16_bf16(a, b0, accC0, 0, 0, 0);
            accC1 = __builtin_amdgcn_mfma_f32_32x32x16_bf16(a, b1, accC1, 0, 0, 0);
        }
    }

    // ---- epilogue: E = 0.5*(Q + C/nel) -> Et (St buffer, swizzled) ----
    __syncthreads();
    ushort_t* Et = St;
    #pragma unroll
    for (int i = 0; i < 2; ++i) {
        v16f c = i ? accC1 : accC0;
        int xl = xws + i * 32 + lo;
        float invn = 1.0f / nel[(b << 10) + x0g + xl];
        #pragma unroll
        for (int g = 0; g < 4; ++g) {
            int d0 = yw * 32 + g * 8 + 4 * hi;          // d0&7 == 4*hi
            int base = xl * 64 + ((((d0 >> 3) ^ (xl & 7)) << 3) | (d0 & 7));
            ushort_t q4[4];
            *(uint2*)q4 = *(const uint2*)&Qt[base];
            ushort_t e4[4];
            #pragma unroll
            for (int r4 = 0; r4 < 4; ++r4) {
                float e = 0.5f * (bfu2f(q4[r4]) + c[g * 4 + r4] * invn);
                e4[r4] = bf16u(e);
            }
            *(uint2*)&Et[base] = *(uint2*)e4;
        }
    }
    __syncthreads();
    // ---- write ET[b][x][h*64+d] coalesced ----
    #pragma unroll
    for (int e = 0; e < 4; ++e) {
        int idx = e * 256 + tid;            // 0..1023 chunks of 8
        int row = idx >> 3, cc = idx & 7;
        uint4 v = *(const uint4*)&Et[row * 64 + ((cc ^ (row & 7)) << 3)];
        *(uint4*)&ETg[((size_t)((b << 10) + x0g + row)) * U_ + h * D_ + cc * 8] = v;
    }
}

// ---------------------------------------------------------------------------
extern "C" void kernel_launch(void* const* d_in, const int* in_sizes, int n_in,
                              void* d_out, int out_size, void* d_ws, size_t ws_size,
                              hipStream_t stream) {
    const float* x    = (const float*)d_in[0];
    const float* y    = (const float*)d_in[1];
    const void*  mask = d_in[2];
    const float* wq   = (const float*)d_in[3];
    const float* wk   = (const float*)d_in[4];
    const float* wo   = (const float*)d_in[5];

    // ws layout (bytes):
    //   [0,        16777216)  xT bf16   -> later ET bf16
    //   [16777216, 33554432)  yT bf16   -> later Kb bf16
    //   [33554432, 50331648)  Ka bf16
    //   [50331648, 50855936)  wq bf16
    //   [50855936, 51380224)  wk bf16
    //   [51380224, 51904512)  wo bf16
    //   [51904512, 54001664)  maskBits u32
    //   [54001664, 54067200)  nel f32
    //   [54067200, ...)       flag int
    char* wsb = (char*)d_ws;
    ushort_t* xT    = (ushort_t*)(wsb);
    ushort_t* yT    = (ushort_t*)(wsb + 16777216);
    ushort_t* Ka    = (ushort_t*)(wsb + 33554432);
    ushort_t* wqb   = (ushort_t*)(wsb + 50331648);
    ushort_t* wkb   = (ushort_t*)(wsb + 50855936);
    ushort_t* wob   = (ushort_t*)(wsb + 51380224);
    uint_t*   mbits = (uint_t*)(wsb + 51904512);
    float*    nel   = (float*)(wsb + 54001664);
    int*      flag  = (int*)(wsb + 54067200);
    ushort_t* ET    = xT;                 // alias: xT dead after Q-GEMM
    ushort_t* Kb    = yT;                 // alias: yT dead after K-GEMM
    ushort_t* Qbf   = (ushort_t*)d_out;   // Q bf16 lives in d_out until final GEMM

    detect_kernel<<<1, 256, 0, stream>>>((const uint_t*)mask, flag);
    nel_kernel<<<(B_ * LX_) / 4, 256, 0, stream>>>(mask, flag, nel);
    maskbits_kernel<<<(B_ * LX_) / 4, 256, 0, stream>>>(mask, flag, mbits);

    cast_bf16<<<U_ * U_ / 1024, 256, 0, stream>>>(wq, wqb);
    cast_bf16<<<U_ * U_ / 1024, 256, 0, stream>>>(wk, wkb);
    cast_bf16<<<U_ * U_ / 1024, 256, 0, stream>>>(wo, wob);
    castT_kernel<<<dim3(LX_ / 64, U_ / 64, B_), 256, 0, stream>>>(x, xT);
    castT_kernel<<<dim3(LY_ / 64, U_ / 64, B_), 256, 0, stream>>>(y, yT);

    gemm_mfma<0><<<dim3(8, 4, B_), 256, 0, stream>>>(wqb, xT, (void*)Qbf);
    gemm_mfma<0><<<dim3(8, 4, B_), 256, 0, stream>>>(wkb, yT, (void*)Ka);
    ktranspose_kernel<<<dim3(LY_ / 64, H_, B_), 256, 0, stream>>>(Ka, Kb);
    attn_mfma<<<dim3(LX_ / 128, H_, B_), 256, 0, stream>>>(Qbf, Ka, Kb, mbits, nel, ET);
    gemm_mfma<1><<<dim3(8, 4, B_), 256, 0, stream>>>(wob, ET, d_out);
}

// Round 4
// 309.459 us; speedup vs baseline: 3.9526x; 1.1240x over previous
//
#include <hip/hip_runtime.h>
#include <stdint.h>
#include <stddef.h>

#define B_  16
#define U_  512
#define LX_ 1024
#define LY_ 1024
#define H_  8
#define D_  64

typedef unsigned short ushort_t;
typedef unsigned int   uint_t;
typedef __bf16 v8bf  __attribute__((ext_vector_type(8)));
typedef float  v16f  __attribute__((ext_vector_type(16)));

__device__ __forceinline__ ushort_t bf16u(float f) {
    uint_t u = __float_as_uint(f);
    uint_t r = (u + 0x7FFFu + ((u >> 16) & 1u)) >> 16;
    return (ushort_t)r;
}
__device__ __forceinline__ float bfu2f(ushort_t u) {
    return __uint_as_float(((uint_t)u) << 16);
}
// RNE-pack two fp32 -> packed bf16x2 (low=f0) using v_perm_b32.
__device__ __forceinline__ uint_t pkbf16(float f0, float f1) {
    uint_t u0 = __float_as_uint(f0), u1 = __float_as_uint(f1);
    u0 = u0 + 0x7FFFu + ((u0 >> 16) & 1u);
    u1 = u1 + 0x7FFFu + ((u1 >> 16) & 1u);
    return __builtin_amdgcn_perm(u1, u0, 0x07060302u);
}
// async global->LDS, 16B/lane. LDS dest is wave-uniform base + lane*16, so
// swizzling must be applied to the GLOBAL source chunk, not the LDS address.
__device__ __forceinline__ void gload16(const void* g, void* l) {
    auto gp = (const __attribute__((address_space(1))) uint32_t*)(uintptr_t)g;
    auto lp = (__attribute__((address_space(3))) uint32_t*)(uintptr_t)l;
    __builtin_amdgcn_global_load_lds(gp, lp, 16, 0, 0);
}

// ---------------------------------------------------------------------------
// Detect mask element width: int32 (all first-1024 words <= 1) vs uint8.
// ---------------------------------------------------------------------------
__global__ void detect_kernel(const uint_t* __restrict__ mask, int* __restrict__ flag) {
    __shared__ int s;
    if (threadIdx.x == 0) s = 0;
    __syncthreads();
    int c = 0;
    for (int i = threadIdx.x; i < 1024; i += 256) c += (mask[i] <= 1u) ? 1 : 0;
    atomicAdd(&s, c);
    __syncthreads();
    if (threadIdx.x == 0) *flag = (s >= 1000) ? 1 : 0;
}

// ---------------------------------------------------------------------------
// Single mask pass: maskBits (ballot) + n_el (popcount). One wave per row.
// ---------------------------------------------------------------------------
__global__ __launch_bounds__(256) void nelmask_kernel(const void* __restrict__ mask,
                                                      const int* __restrict__ flag,
                                                      float* __restrict__ nel,
                                                      uint_t* __restrict__ mb) {
    int row  = blockIdx.x * 4 + (threadIdx.x >> 6);   // b*1024 + x
    int lane = threadIdx.x & 63;
    const int isInt = *flag;
    const uint8_t* m8  = (const uint8_t*)mask + (size_t)row * LY_;
    const int*     m32 = (const int*)mask + (size_t)row * LY_;
    int cnt = 0;
    for (int yg = 0; yg < LY_ / 64; ++yg) {
        int y = yg * 64 + lane;
        bool p = isInt ? (m32[y] != 0) : (m8[y] != 0);
        unsigned long long bal = __ballot(p);
        if (lane == 0) {
            mb[(size_t)row * 32 + yg * 2]     = (uint_t)bal;
            mb[(size_t)row * 32 + yg * 2 + 1] = (uint_t)(bal >> 32);
            cnt += __popcll(bal);
        }
    }
    if (lane == 0) nel[row] = (float)(cnt > 0 ? cnt : 1);
}

// ---------------------------------------------------------------------------
// All three 512x512 weights -> bf16 in one dispatch (blockIdx.y selects).
// ---------------------------------------------------------------------------
__global__ __launch_bounds__(256) void castw_kernel(const float* __restrict__ w0,
                                                    const float* __restrict__ w1,
                                                    const float* __restrict__ w2,
                                                    ushort_t* __restrict__ o0,
                                                    ushort_t* __restrict__ o1,
                                                    ushort_t* __restrict__ o2) {
    const float* s = blockIdx.y == 0 ? w0 : (blockIdx.y == 1 ? w1 : w2);
    ushort_t*    d = blockIdx.y == 0 ? o0 : (blockIdx.y == 1 ? o1 : o2);
    int i = (blockIdx.x * 256 + threadIdx.x) * 4;
    float4 v = *(const float4*)&s[i];
    ushort4 p;
    p.x = bf16u(v.x); p.y = bf16u(v.y); p.z = bf16u(v.z); p.w = bf16u(v.w);
    *(ushort4*)&d[i] = p;
}

// ---------------------------------------------------------------------------
// x and y [b][u][l] fp32 -> [b][l][u] bf16, 64x64 LDS tiles. z = b + 16*sel.
// ---------------------------------------------------------------------------
__global__ __launch_bounds__(256) void castT_kernel(const float* __restrict__ X,
                                                    const float* __restrict__ Y,
                                                    ushort_t* __restrict__ XT,
                                                    ushort_t* __restrict__ YT) {
    const int l0 = blockIdx.x * 64;
    const int u0 = blockIdx.y * 64;
    const int b  = blockIdx.z & 15;
    const int sel = blockIdx.z >> 4;
    const float* S = sel ? Y : X;
    ushort_t*  Dst = sel ? YT : XT;
    __shared__ ushort_t T[64][72];
    const int tid = threadIdx.x;
    #pragma unroll
    for (int e = 0; e < 4; ++e) {
        int ci = e * 256 + tid;            // 0..1023 float4s
        int r = ci >> 4, c4 = (ci & 15) * 4;
        float4 v = *(const float4*)&S[((size_t)(b * U_ + u0 + r) << 10) + l0 + c4];
        T[r][c4 + 0] = bf16u(v.x); T[r][c4 + 1] = bf16u(v.y);
        T[r][c4 + 2] = bf16u(v.z); T[r][c4 + 3] = bf16u(v.w);
    }
    __syncthreads();
    #pragma unroll
    for (int e = 0; e < 2; ++e) {
        int ci = e * 256 + tid;            // 0..511 chunks of 8
        int lr = ci >> 3, cc = ci & 7;
        ushort_t tmp[8];
        #pragma unroll
        for (int j = 0; j < 8; ++j) tmp[j] = T[cc * 8 + j][lr];
        *(uint4*)&Dst[((size_t)((b << 10) + l0 + lr)) * U_ + u0 + cc * 8] = *(uint4*)tmp;
    }
}

// ---------------------------------------------------------------------------
// Generalized bf16 MFMA GEMM: Out[b][m][n] = sum_k A_b[m][k] * B_b[n][k]
// K = 512 (= lda = ldb). 128x128 tile, BK=64, gload16 staging, src-xor swizzle.
// aStr/bStr: per-batch element strides (0 = shared). Out: oStr*b + m*ldOut + n.
// ---------------------------------------------------------------------------
template <int OUTF32>
__global__ __launch_bounds__(256) void gemm_mfma(const ushort_t* __restrict__ A, size_t aStr,
                                                 const ushort_t* __restrict__ Bm, size_t bStr,
                                                 void* __restrict__ Out, size_t oStr, int ldOut) {
    const int n0 = blockIdx.x * 128;
    const int m0 = blockIdx.y * 128;
    const int b  = blockIdx.z;
    __shared__ __align__(16) ushort_t As[128 * 64];
    __shared__ __align__(16) ushort_t Bs[128 * 64];
    const int tid = threadIdx.x;
    const ushort_t* Ab = A + aStr * b;
    const ushort_t* Bb = Bm + bStr * b;

    const int w = tid >> 6, lane = tid & 63, lo = lane & 31, hi = lane >> 5;
    const int wm = (w >> 1) * 64, wn = (w & 1) * 64;

    v16f acc00, acc01, acc10, acc11;
    #pragma unroll
    for (int i = 0; i < 16; ++i) { acc00[i] = 0.f; acc01[i] = 0.f; acc10[i] = 0.f; acc11[i] = 0.f; }

    for (int kk = 0; kk < 8; ++kk) {
        const int k0 = kk * 64;
        #pragma unroll
        for (int e = 0; e < 4; ++e) {
            int ci = e * 256 + tid;          // 0..1023 16B chunks
            int r = ci >> 3, c = ci & 7;
            int g = (c ^ (r & 7)) << 3;      // swizzle on SOURCE chunk
            gload16(&Ab[(size_t)(m0 + r) * U_ + k0 + g], &As[ci * 8]);
            gload16(&Bb[(size_t)(n0 + r) * U_ + k0 + g], &Bs[ci * 8]);
        }
        __syncthreads();
        #pragma unroll
        for (int ks = 0; ks < 4; ++ks) {
            int ch = ks * 2 + hi;
            int rA0 = wm + lo, rA1 = wm + 32 + lo;
            int rB0 = wn + lo, rB1 = wn + 32 + lo;
            v8bf a0 = *(v8bf*)&As[rA0 * 64 + ((ch ^ (rA0 & 7)) << 3)];
            v8bf a1 = *(v8bf*)&As[rA1 * 64 + ((ch ^ (rA1 & 7)) << 3)];
            v8bf b0 = *(v8bf*)&Bs[rB0 * 64 + ((ch ^ (rB0 & 7)) << 3)];
            v8bf b1 = *(v8bf*)&Bs[rB1 * 64 + ((ch ^ (rB1 & 7)) << 3)];
            acc00 = __builtin_amdgcn_mfma_f32_32x32x16_bf16(a0, b0, acc00, 0, 0, 0);
            acc01 = __builtin_amdgcn_mfma_f32_32x32x16_bf16(a0, b1, acc01, 0, 0, 0);
            acc10 = __builtin_amdgcn_mfma_f32_32x32x16_bf16(a1, b0, acc10, 0, 0, 0);
            acc11 = __builtin_amdgcn_mfma_f32_32x32x16_bf16(a1, b1, acc11, 0, 0, 0);
        }
        __syncthreads();
    }

    #pragma unroll
    for (int mi = 0; mi < 2; ++mi) {
        #pragma unroll
        for (int nj = 0; nj < 2; ++nj) {
            v16f c = mi ? (nj ? acc11 : acc10) : (nj ? acc01 : acc00);
            int n = n0 + wn + nj * 32 + lo;
            #pragma unroll
            for (int r = 0; r < 16; ++r) {
                int m = m0 + wm + mi * 32 + (r & 3) + 8 * (r >> 2) + 4 * hi;
                size_t addr = oStr * b + (size_t)m * ldOut + n;
                if (OUTF32) ((float*)Out)[addr] = c[r];
                else        ((ushort_t*)Out)[addr] = bf16u(c[r]);
            }
        }
    }
}

// ---------------------------------------------------------------------------
// Ka[b][u=h*64+d][y] bf16 -> Kb[b][h][y][d] bf16 (64x64 LDS transpose)
// ---------------------------------------------------------------------------
__global__ __launch_bounds__(256) void ktranspose_kernel(const ushort_t* __restrict__ Ka,
                                                         ushort_t* __restrict__ Kb) {
    const int y0 = blockIdx.x * 64;
    const int h  = blockIdx.y;
    const int b  = blockIdx.z;
    __shared__ ushort_t T[64][72];
    const int tid = threadIdx.x;

    #pragma unroll
    for (int e = 0; e < 2; ++e) {
        int idx = e * 256 + tid;
        int d = idx >> 3, c = idx & 7;
        uint4 v = *(const uint4*)&Ka[((size_t)(b * U_ + h * D_ + d) << 10) + y0 + c * 8];
        *(uint4*)&T[d][c * 8] = v;
    }
    __syncthreads();
    #pragma unroll
    for (int e = 0; e < 2; ++e) {
        int idx = e * 256 + tid;
        int yy = idx >> 3, dc = idx & 7;
        ushort_t tmp[8];
        #pragma unroll
        for (int j = 0; j < 8; ++j) tmp[j] = T[dc * 8 + j][yy];
        *(uint4*)&Kb[(((size_t)(b * H_ + h) << 10) + y0 + yy) * D_ + dc * 8] = *(uint4*)tmp;
    }
}

// ---------------------------------------------------------------------------
// Fused bf16-MFMA attention. QT[b][x][u] bf16 in, ET[b][x][u] bf16 out.
// 1-D grid of 1024: bh = id&127 (XCD-grouped), xt = id>>7. 256 thr, 48 KB LDS.
// Q fragments hoisted out of the y-loop; all staging via gload16.
// ---------------------------------------------------------------------------
__global__ __launch_bounds__(256, 3) void attn_mfma(const ushort_t* __restrict__ QTg,
                                                    const ushort_t* __restrict__ Ka_g,
                                                    const ushort_t* __restrict__ Kb_g,
                                                    const uint_t* __restrict__ mbits,
                                                    const float* __restrict__ nel,
                                                    ushort_t* __restrict__ ETg) {
    const int tid = threadIdx.x;
    const int id  = blockIdx.x;
    const int bh  = id & 127;          // same-bh blocks -> same XCD (id%8 heuristic)
    const int x0g = (id >> 7) * 128;
    const int b = bh >> 3, h = bh & 7;

    __shared__ __align__(16) ushort_t Qt[128 * 64];
    __shared__ __align__(16) ushort_t Kb[64 * 64];
    __shared__ __align__(16) ushort_t Ka[64 * 64];
    __shared__ __align__(16) ushort_t St[128 * 64];

    const int w    = tid >> 6;
    const int lane = tid & 63;
    const int lo   = lane & 31;
    const int hi   = lane >> 5;
    const int yw   = w & 1;            // S: y-sub;  C: d-sub = yw*32
    const int xws  = (w >> 1) * 64;    // x-subs xws + {0,32}

    // ---- stage Qt[x][d] via gload16 (src-swizzled, no scatter) ----
    const ushort_t* Qsrc = QTg + ((size_t)(b * LX_ + x0g)) * U_ + h * D_;
    #pragma unroll
    for (int e = 0; e < 4; ++e) {
        int ci = e * 256 + tid;
        int r = ci >> 3, c = ci & 7;
        gload16(&Qsrc[(size_t)r * U_ + ((c ^ (r & 7)) << 3)], &Qt[ci * 8]);
    }
    const ushort_t* KaBase = Ka_g + ((size_t)(b * U_ + h * D_)) * LY_;
    const ushort_t* KbBase = Kb_g + ((size_t)(b * H_ + h)) * LY_ * D_;

    __syncthreads();
    // ---- hoist Q B-fragments (loop-invariant): 8 x v8bf = 32 VGPR ----
    v8bf qf0[4], qf1[4];
    {
        int rB0 = xws + lo, rB1 = xws + 32 + lo;
        #pragma unroll
        for (int kt = 0; kt < 4; ++kt) {
            int ch = kt * 2 + hi;
            qf0[kt] = *(v8bf*)&Qt[rB0 * 64 + ((ch ^ (rB0 & 7)) << 3)];
            qf1[kt] = *(v8bf*)&Qt[rB1 * 64 + ((ch ^ (rB1 & 7)) << 3)];
        }
    }

    v16f accC0, accC1;
    #pragma unroll
    for (int i = 0; i < 16; ++i) { accC0[i] = 0.f; accC1[i] = 0.f; }

    const int rowA = yw * 32 + lo;
    const int rB0  = xws + lo, rB1 = xws + 32 + lo;

    for (int y0 = 0; y0 < LY_; y0 += 64) {
        __syncthreads();
        // ---- stage Kb[y][d], Ka[d][y] via gload16 ----
        #pragma unroll
        for (int e = 0; e < 2; ++e) {
            int ci = e * 256 + tid;
            int r = ci >> 3, c = ci & 7;
            int g8 = (c ^ (r & 7)) << 3;
            gload16(&KbBase[(size_t)(y0 + r) * D_ + g8], &Kb[ci * 8]);
            gload16(&KaBase[(size_t)r * LY_ + y0 + g8], &Ka[ci * 8]);
        }
        __syncthreads();

        // ---- S-phase: S^T = Kb * Qt^T (B-frags from registers) ----
        v16f s0, s1;
        #pragma unroll
        for (int i = 0; i < 16; ++i) { s0[i] = 0.f; s1[i] = 0.f; }
        #pragma unroll
        for (int kt = 0; kt < 4; ++kt) {
            int ch = kt * 2 + hi;
            v8bf a = *(v8bf*)&Kb[rowA * 64 + ((ch ^ (rowA & 7)) << 3)];
            s0 = __builtin_amdgcn_mfma_f32_32x32x16_bf16(a, qf0[kt], s0, 0, 0, 0);
            s1 = __builtin_amdgcn_mfma_f32_32x32x16_bf16(a, qf1[kt], s1, 0, 0, 0);
        }
        // ---- relu (scale folded into epilogue) + bitwise mask + bf16 pack ----
        #pragma unroll
        for (int i = 0; i < 2; ++i) {
            v16f s = i ? s1 : s0;
            int xl = xws + i * 32 + lo;
            uint_t wbits = mbits[((size_t)(b * LX_ + x0g + xl)) * 32 + (y0 >> 5) + yw];
            #pragma unroll
            for (int g = 0; g < 4; ++g) {
                uint_t w2 = wbits >> (g * 8 + 4 * hi);
                float f0 = fmaxf(s[g * 4 + 0], 0.f), f1 = fmaxf(s[g * 4 + 1], 0.f);
                float f2 = fmaxf(s[g * 4 + 2], 0.f), f3 = fmaxf(s[g * 4 + 3], 0.f);
                uint_t m0 = ((w2 & 1u) * 0xFFFFu) | ((w2 & 2u) * 0x7FFF8000u);
                uint_t m1 = (((w2 >> 2) & 1u) * 0xFFFFu) | (((w2 >> 2) & 2u) * 0x7FFF8000u);
                uint2 pk;
                pk.x = pkbf16(f0, f1) & m0;
                pk.y = pkbf16(f2, f3) & m1;
                int yb = yw * 32 + g * 8 + 4 * hi;
                *(uint2*)&St[xl * 64 + (((yb >> 3) ^ (xl & 7)) << 3) + (yb & 7)] = pk;
            }
        }
        __syncthreads();

        // ---- C-phase: C[d][x] += Ka * St^T ----
        #pragma unroll
        for (int kt = 0; kt < 4; ++kt) {
            int ch = kt * 2 + hi;
            v8bf a  = *(v8bf*)&Ka[rowA * 64 + ((ch ^ (rowA & 7)) << 3)];
            v8bf b0 = *(v8bf*)&St[rB0 * 64 + ((ch ^ (rB0 & 7)) << 3)];
            v8bf b1 = *(v8bf*)&St[rB1 * 64 + ((ch ^ (rB1 & 7)) << 3)];
            accC0 = __builtin_amdgcn_mfma_f32_32x32x16_bf16(a, b0, accC0, 0, 0, 0);
            accC1 = __builtin_amdgcn_mfma_f32_32x32x16_bf16(a, b1, accC1, 0, 0, 0);
        }
    }

    // ---- epilogue: E = 0.5*Q + C*(0.0625/nel) -> Et (reuse St, swizzled) ----
    __syncthreads();
    ushort_t* Et = St;
    #pragma unroll
    for (int i = 0; i < 2; ++i) {
        v16f c = i ? accC1 : accC0;
        int xl = xws + i * 32 + lo;
        float invn = 0.0625f / nel[b * LX_ + x0g + xl];
        #pragma unroll
        for (int g = 0; g < 4; ++g) {
            int d0 = yw * 32 + g * 8 + 4 * hi;          // d0&7 == 4*hi
            int base = xl * 64 + ((((d0 >> 3) ^ (xl & 7)) << 3) | (d0 & 7));
            ushort_t q4[4];
            *(uint2*)q4 = *(const uint2*)&Qt[base];
            ushort_t e4[4];
            #pragma unroll
            for (int r4 = 0; r4 < 4; ++r4) {
                float e = 0.5f * bfu2f(q4[r4]) + c[g * 4 + r4] * invn;
                e4[r4] = bf16u(e);
            }
            *(uint2*)&Et[base] = *(uint2*)e4;
        }
    }
    __syncthreads();
    // ---- write ET[b][x][h*64+d] coalesced (un-swizzle on read) ----
    #pragma unroll
    for (int e = 0; e < 4; ++e) {
        int idx = e * 256 + tid;
        int row = idx >> 3, cc = idx & 7;
        uint4 v = *(const uint4*)&Et[row * 64 + ((cc ^ (row & 7)) << 3)];
        *(uint4*)&ETg[((size_t)(b * LX_ + x0g + row)) * U_ + h * D_ + cc * 8] = v;
    }
}

// ---------------------------------------------------------------------------
extern "C" void kernel_launch(void* const* d_in, const int* in_sizes, int n_in,
                              void* d_out, int out_size, void* d_ws, size_t ws_size,
                              hipStream_t stream) {
    const float* x    = (const float*)d_in[0];
    const float* y    = (const float*)d_in[1];
    const void*  mask = d_in[2];
    const float* wq   = (const float*)d_in[3];
    const float* wk   = (const float*)d_in[4];
    const float* wo   = (const float*)d_in[5];

    // ws layout (bytes):
    //   [0,        16777216)  xT bf16   -> later ET bf16
    //   [16777216, 33554432)  yT bf16   -> later Kb bf16
    //   [33554432, 50331648)  Ka bf16
    //   [50331648, 50855936)  wq bf16
    //   [50855936, 51380224)  wk bf16
    //   [51380224, 51904512)  wo bf16
    //   [51904512, 54001664)  maskBits u32
    //   [54001664, 54067200)  nel f32
    //   [54067200, ...)       flag int
    char* wsb = (char*)d_ws;
    ushort_t* xT    = (ushort_t*)(wsb);
    ushort_t* yT    = (ushort_t*)(wsb + 16777216);
    ushort_t* Ka    = (ushort_t*)(wsb + 33554432);
    ushort_t* wqb   = (ushort_t*)(wsb + 50331648);
    ushort_t* wkb   = (ushort_t*)(wsb + 50855936);
    ushort_t* wob   = (ushort_t*)(wsb + 51380224);
    uint_t*   mbits = (uint_t*)(wsb + 51904512);
    float*    nel   = (float*)(wsb + 54001664);
    int*      flag  = (int*)(wsb + 54067200);
    ushort_t* ET    = xT;                 // alias: xT dead after Q-GEMM
    ushort_t* Kb    = yT;                 // alias: yT dead after K-GEMM
    ushort_t* QT    = (ushort_t*)d_out;   // QT[b][x][u] bf16 lives in d_out

    detect_kernel<<<1, 256, 0, stream>>>((const uint_t*)mask, flag);
    nelmask_kernel<<<(B_ * LX_) / 4, 256, 0, stream>>>(mask, flag, nel, mbits);
    castw_kernel<<<dim3(U_ * U_ / 1024, 3), 256, 0, stream>>>(wq, wk, wo, wqb, wkb, wob);
    castT_kernel<<<dim3(16, 8, 32), 256, 0, stream>>>(x, y, xT, yT);

    // QT[b][x][u] = xT[b] (M=1024) x wq (N=512)
    gemm_mfma<0><<<dim3(4, 8, B_), 256, 0, stream>>>(
        xT, (size_t)LX_ * U_, wqb, 0, (void*)QT, (size_t)LX_ * U_, U_);
    // Ka[b][u][y] = wk (M=512) x yT[b] (N=1024)
    gemm_mfma<0><<<dim3(8, 4, B_), 256, 0, stream>>>(
        wkb, 0, yT, (size_t)LY_ * U_, (void*)Ka, (size_t)U_ * LY_, LY_);
    ktranspose_kernel<<<dim3(LY_ / 64, H_, B_), 256, 0, stream>>>(Ka, Kb);
    attn_mfma<<<1024, 256, 0, stream>>>(QT, Ka, Kb, mbits, nel, ET);
    // out[b][u][x] fp32 = wo (M=512) x ET[b] (N=1024)
    gemm_mfma<1><<<dim3(8, 4, B_), 256, 0, stream>>>(
        wob, 0, ET, (size_t)LX_ * U_, d_out, (size_t)U_ * LX_, LX_);
}